// Round 4
// baseline (292.205 us; speedup 1.0000x reference)
//
#include <hip/hip_runtime.h>
#include <math.h>

#define BB 256
#define LL 500
#define EE 300
#define NROWS (BB * LL)      // 128000
#define ND 18                // dot vectors: aw3 r0-2, cw3, aw5 r0-4, cw5, aw7 r0-6, cw7
#define WSTR 20              // wt row stride in floats (80 B, float4-aligned)
#define KT 16                // k per tile
#define NTILES 19            // ceil(300/16); last tile k=288..303 zero-padded
#define KPAD (NTILES * KT)   // 304
#define WR 64                // dot rows per wave-job (= 58 outputs + 6 halo)
#define OPW 58               // outputs per wave-job
#define JPB 9                // jobs per batch (9*58 = 522 >= 500)
#define XSTR 17              // x LDS row stride in floats: gcd(17,32)=1 -> conflict-free
#define DSTR 19              // dots LDS row stride

// ---------------------------------------------------------------------------
// R10: mapping inversion. R9 disproved the lockstep theory (removing all
// barriers changed nothing); the invariant ~20k-cyc per-wave job time is the
// LDS-weight latency chain + register spill (WRITE_SIZE showed ~1MB scratch:
// xall 80 + acc 72 > 132 VGPR). Structural fix: weights become WAVE-UNIFORM
// (k-major wt[] built by a tiny prepass into d_ws, read via s_load on the
// scalar pipe; v_fmac with SGPR operand), and each lane owns ONE ROW -> acc
// is 18 VGPRs, NO cross-lane reduce, no spill. x streams through a private
// per-wave LDS slice in double-buffered k-tiles of 16 (stride 17 = exactly
// 2 lanes/bank on reads AND writes), next tile's coalesced float4 loads
// issued under the current tile's 288 FMAs. Zero barriers; the +-3 epilogue
// window goes through a dlds patch aliasing the dead x slice (same-wave
// lgkmcnt(0) only, proven in R9). Halo waste drops 39% -> 10%.
// Budget/CU: VALU ~11us, LDS ~11us, HBM floor 24.4us -> memory-bound.
// ---------------------------------------------------------------------------

__global__ void wt_transpose(
    const float* __restrict__ aw3, const float* __restrict__ aw5,
    const float* __restrict__ aw7, const float* __restrict__ cw3,
    const float* __restrict__ cw5, const float* __restrict__ cw7,
    float* __restrict__ wt)
{
    const int idx = blockIdx.x * 256 + threadIdx.x;
    if (idx >= KPAD * WSTR) return;
    const int k = idx / WSTR;
    const int d = idx - k * WSTR;
    float v = 0.0f;
    if (k < EE && d < ND) {
        if      (d < 3)  v = aw3[d * EE + k];
        else if (d == 3) v = cw3[k];
        else if (d < 9)  v = aw5[(d - 4) * EE + k];
        else if (d == 9) v = cw5[k];
        else if (d < 17) v = aw7[(d - 10) * EE + k];
        else             v = cw7[k];
    }
    wt[idx] = v;
}

__global__ __launch_bounds__(256) void fused_kernel(
    const float* __restrict__ x, const float* __restrict__ wt,
    const float* __restrict__ ab3, const float* __restrict__ cb3,
    const float* __restrict__ ab5, const float* __restrict__ cb5,
    const float* __restrict__ ab7, const float* __restrict__ cb7,
    float* __restrict__ out)
{
    // 4 waves x 2 buffers x (64 rows x 17 floats) = 34816 B -> 4 blocks/CU
    __shared__ float xlds[4][2][WR * XSTR];

    const int tid   = threadIdx.x;
    const int wave  = tid >> 6;
    const int lane  = tid & 63;
    const int job   = blockIdx.x * 4 + wave;       // 0..2303
    const int batch = job / JPB;
    const int t     = job - batch * JPB;           // 0..8
    const int l0    = t * OPW - 3;                 // global l of local row 0

    const float* xbb = x + (size_t)batch * LL * EE;
    float* xw = &xlds[wave][0][0];                 // this wave's 2176-float slice

    // staging geometry: pass p covers rows p*16..p*16+15; 4 lanes per row,
    // lane provides float4 #sc of the 16-float k-window
    const int srow = lane >> 2;                    // 0..15
    const int sc   = lane & 3;                     // 0..3

    const float* srp[4];
#pragma unroll
    for (int p = 0; p < 4; ++p) {
        int l = l0 + srow + p * 16;
        l = l < 0 ? 0 : (l >= LL ? LL - 1 : l);
        srp[p] = xbb + (size_t)l * EE;
    }

    // ---- prologue: stage tile 0 into buffer 0 ----
    float4 g[4];
#pragma unroll
    for (int p = 0; p < 4; ++p) g[p] = *(const float4*)(srp[p] + sc * 4);
#pragma unroll
    for (int p = 0; p < 4; ++p) {
        const int base = (srow + p * 16) * XSTR + sc * 4;
        xw[base + 0] = g[p].x; xw[base + 1] = g[p].y;
        xw[base + 2] = g[p].z; xw[base + 3] = g[p].w;
    }

    float acc[ND];
#pragma unroll
    for (int d = 0; d < ND; ++d) acc[d] = 0.0f;

#pragma unroll 1
    for (int tt = 0; tt < NTILES; ++tt) {
        // issue next tile's global loads (in flight under this tile's FMAs)
        const int nt = tt + 1;
        if (nt < NTILES) {
            const int k0 = nt * KT;
            const bool tail = (nt == NTILES - 1) && (sc == 3);  // k 300..303
#pragma unroll
            for (int p = 0; p < 4; ++p) {
                if (tail) { g[p].x = 0.f; g[p].y = 0.f; g[p].z = 0.f; g[p].w = 0.f; }
                else      { g[p] = *(const float4*)(srp[p] + k0 + sc * 4); }
            }
        }

        // compute this tile: 16 private-row LDS reads + 288 FMA w/ SGPR weights
        const float* xb   = xw + (tt & 1) * (WR * XSTR) + lane * XSTR;
        const float* wrow = wt + tt * KT * WSTR;     // uniform -> s_load

        float xv[KT];
#pragma unroll
        for (int kk = 0; kk < KT; ++kk) xv[kk] = xb[kk];
#pragma unroll
        for (int kk = 0; kk < KT; ++kk) {
#pragma unroll
            for (int d = 0; d < ND; ++d)
                acc[d] = fmaf(wrow[kk * WSTR + d], xv[kk], acc[d]);
        }

        // land next tile in the other buffer (same-wave in-order LDS: these
        // writes cannot pass this tile's reads; next tile's reads wait via
        // compiler lgkmcnt)
        if (nt < NTILES) {
            float* xn = xw + (nt & 1) * (WR * XSTR);
#pragma unroll
            for (int p = 0; p < 4; ++p) {
                const int base = (srow + p * 16) * XSTR + sc * 4;
                xn[base + 0] = g[p].x; xn[base + 1] = g[p].y;
                xn[base + 2] = g[p].z; xn[base + 3] = g[p].w;
            }
        }
    }

    // ---- dots -> dlds patch (aliases dead x slice; 64x19 = 1216 <= 2176) ----
    {
        const int lg = l0 + lane;
        const float vf = (lg >= 0 && lg < LL) ? 1.0f : 0.0f;
#pragma unroll
        for (int d = 0; d < ND; ++d) xw[lane * DSTR + d] = acc[d] * vf;
    }
    asm volatile("s_waitcnt lgkmcnt(0)" ::: "memory");   // same-wave visibility

    // ---- epilogue: lane = center row, all 3 branches, no barrier ----
    if (lane >= 3 && lane < 3 + OPW) {
        const int lo = l0 + lane;
        if (lo < LL) {
            const int r = batch * LL + lo;
            const float cen3 = xw[lane * DSTR + 3];
            const float cen5 = xw[lane * DSTR + 9];
            const float cen7 = xw[lane * DSTR + 17];
            {
                float pre = 0.0f;
#pragma unroll
                for (int tp = 0; tp < 3; ++tp) pre += xw[(lane + tp - 1) * DSTR + tp];
                const float s = 1.0f / (1.0f + expf(-(pre + ab3[0])));
                out[r] = tanhf(s * cen3 + cb3[0]);
            }
            {
                float pre = 0.0f;
#pragma unroll
                for (int tp = 0; tp < 5; ++tp) pre += xw[(lane + tp - 2) * DSTR + 4 + tp];
                const float s = 1.0f / (1.0f + expf(-(pre + ab5[0])));
                out[NROWS + r] = tanhf(s * cen5 + cb5[0]);
            }
            {
                float pre = 0.0f;
#pragma unroll
                for (int tp = 0; tp < 7; ++tp) pre += xw[(lane + tp - 3) * DSTR + 10 + tp];
                const float s = 1.0f / (1.0f + expf(-(pre + ab7[0])));
                out[2 * NROWS + r] = tanhf(s * cen7 + cb7[0]);
            }
        }
    }
}

extern "C" void kernel_launch(void* const* d_in, const int* in_sizes, int n_in,
                              void* d_out, int out_size, void* d_ws, size_t ws_size,
                              hipStream_t stream) {
    const float* x   = (const float*)d_in[0];
    const float* aw3 = (const float*)d_in[1];
    const float* ab3 = (const float*)d_in[2];
    const float* cw3 = (const float*)d_in[3];
    const float* cb3 = (const float*)d_in[4];
    const float* aw5 = (const float*)d_in[5];
    const float* ab5 = (const float*)d_in[6];
    const float* cw5 = (const float*)d_in[7];
    const float* cb5 = (const float*)d_in[8];
    const float* aw7 = (const float*)d_in[9];
    const float* ab7 = (const float*)d_in[10];
    const float* cw7 = (const float*)d_in[11];
    const float* cb7 = (const float*)d_in[12];

    float* wt  = (float*)d_ws;   // 304 x 20 floats = 24.3 KB in workspace
    float* out = (float*)d_out;  // [out3 | out5 | out7]

    // prepass: k-major zero-padded weight matrix (stream-ordered before main)
    wt_transpose<<<(KPAD * WSTR + 255) / 256, 256, 0, stream>>>(
        aw3, aw5, aw7, cw3, cw5, cw7, wt);

    // 2304 wave-jobs (256 batches x 9), 4 independent waves per block
    fused_kernel<<<(BB * JPB) / 4, 256, 0, stream>>>(
        x, wt, ab3, cb3, ab5, cb5, ab7, cb7, out);
}